// Round 8
// baseline (196.368 us; speedup 1.0000x reference)
//
#include <hip/hip_runtime.h>
#include <cstddef>

#define NN 100000
#define NE 640000
#define NB_SCAN 391   // ceil(NN/256)

typedef short  short8   __attribute__((ext_vector_type(8)));
typedef float  f32x4    __attribute__((ext_vector_type(4)));
typedef ushort ushort4v __attribute__((ext_vector_type(4)));

__device__ __forceinline__ short f2bf(float f) {   // RNE f32->bf16
    union { float f; unsigned u; } v; v.f = f;
    unsigned r = (v.u + 0x7fffu + ((v.u >> 16) & 1u)) >> 16;
    return (short)r;
}

// K0: weight bf16-transpose + in-degree histogram. (node_score/attn_b are
// DEAD: per-segment softmax is shift-invariant, the per-dst constant cancels.)
__global__ __launch_bounds__(256) void k_pre(
    const float* __restrict__ W1, const float* __restrict__ W2,
    const float* __restrict__ evW, const int* __restrict__ dst_idx,
    int* __restrict__ count,
    ushort* __restrict__ W1t, ushort* __restrict__ W2t, ushort* __restrict__ evWt)
{
    const int gid = blockIdx.x * 256 + threadIdx.x;   // grid 2500 -> gid < NE
    if (gid < 16384) {
        const int n = gid >> 7, k = gid & 127;
        W1t[gid] = (ushort)f2bf(W1[k * 128 + n]);
        W2t[gid] = (ushort)f2bf(W2[k * 128 + n]);
        if (gid < 8192) {
            const int n2 = gid >> 6, k2 = gid & 63;
            evWt[gid] = (ushort)f2bf(evW[k2 * 128 + n2]);
        }
    }
    atomicAdd(&count[dst_idx[gid]], 1);               // 2500*256 == NE exactly
}

// Scan A: per-block sums
__global__ __launch_bounds__(256) void k_scan_bsum(
    const int* __restrict__ count, int* __restrict__ bsum)
{
    __shared__ int s[256];
    const int t = threadIdx.x, i = blockIdx.x * 256 + t;
    s[t] = (i < NN) ? count[i] : 0;
    __syncthreads();
    for (int off = 128; off; off >>= 1) { if (t < off) s[t] += s[t + off]; __syncthreads(); }
    if (t == 0) bsum[blockIdx.x] = s[0];
}

// Scan B (merged): each block self-computes its prefix over bsum, then
// in-block exclusive scan -> rowptr. Last block writes rowptr[NN] = NE.
__global__ __launch_bounds__(256) void k_scan_final(
    const int* __restrict__ count, const int* __restrict__ bsum,
    int* __restrict__ rowptr)
{
    __shared__ int s[256];
    __shared__ int red[4];
    const int t = threadIdx.x, i = blockIdx.x * 256 + t;
    const int v = (i < NN) ? count[i] : 0;
    s[t] = v;

    int part = 0;
    for (int b = t; b < blockIdx.x; b += 256) part += bsum[b];
    #pragma unroll
    for (int off = 32; off; off >>= 1) part += __shfl_xor(part, off);
    if ((t & 63) == 0) red[t >> 6] = part;
    __syncthreads();
    const int boff = red[0] + red[1] + red[2] + red[3];

    for (int off = 1; off < 256; off <<= 1) {
        const int x = (t >= off) ? s[t - off] : 0;
        __syncthreads();
        s[t] += x;
        __syncthreads();
    }
    if (i < NN) rowptr[i] = boff + s[t] - v;
    if (blockIdx.x == NB_SCAN - 1 && t == 255) rowptr[NN] = boff + s[255];
}

// K2: build permutation grouping edges by dst (CSR)
__global__ __launch_bounds__(256) void k_permute(
    const int* __restrict__ dst_idx, const int* __restrict__ rowptr,
    int* cursor, int* __restrict__ perm)
{
    const int e = blockIdx.x * 256 + threadIdx.x;     // grid 2500 exact
    const int dd = dst_idx[e];
    perm[rowptr[dd] + atomicAdd(&cursor[dd], 1)] = e;
}

// K3: single-pass gather + ONLINE segment softmax + aggregation.
__global__ __launch_bounds__(256) void k_agg_gather(
    const float* __restrict__ ef, const float* __restrict__ attn_W,
    const int* __restrict__ perm, const int* __restrict__ rowptr,
    ushort* __restrict__ agg, float* __restrict__ msum)
{
    const int t  = threadIdx.x;
    const int sl = t & 15;
    const int n  = blockIdx.x * 16 + (t >> 4);   // grid 6250 -> exact
    const int beg = rowptr[n], end = rowptr[n + 1];

    float4 wl;   // mean_h attn_W rows 128+sl*4 .. +3
    {
        const float4 r0 = *reinterpret_cast<const float4*>(attn_W + (128 + sl * 4 + 0) * 4);
        const float4 r1 = *reinterpret_cast<const float4*>(attn_W + (128 + sl * 4 + 1) * 4);
        const float4 r2 = *reinterpret_cast<const float4*>(attn_W + (128 + sl * 4 + 2) * 4);
        const float4 r3 = *reinterpret_cast<const float4*>(attn_W + (128 + sl * 4 + 3) * 4);
        wl.x = 0.25f * (r0.x + r0.y + r0.z + r0.w);
        wl.y = 0.25f * (r1.x + r1.y + r1.z + r1.w);
        wl.z = 0.25f * (r2.x + r2.y + r2.z + r2.w);
        wl.w = 0.25f * (r3.x + r3.y + r3.z + r3.w);
    }

    float m  = -3.0e38f;
    float se = 0.f;
    f32x4 acc = {0.f, 0.f, 0.f, 0.f};

    for (int i = beg; i < end; i += 8) {
        int pe[8];
        #pragma unroll
        for (int j = 0; j < 8; ++j)
            pe[j] = perm[(i + j < end) ? (i + j) : beg];
        float4 v[8];
        #pragma unroll
        for (int j = 0; j < 8; ++j)
            v[j] = *reinterpret_cast<const float4*>(ef + (size_t)pe[j] * 64 + sl * 4);
        float sc[8];
        #pragma unroll
        for (int j = 0; j < 8; ++j) {
            float x = v[j].x * wl.x + v[j].y * wl.y + v[j].z * wl.z + v[j].w * wl.w;
            #pragma unroll
            for (int off = 8; off; off >>= 1) x += __shfl_xor(x, off, 16);
            sc[j] = (i + j < end) ? x : -3.0e38f;
        }
        float bm = m;
        #pragma unroll
        for (int j = 0; j < 8; ++j) bm = fmaxf(bm, sc[j]);
        const float r = __expf(m - bm);
        acc[0] *= r; acc[1] *= r; acc[2] *= r; acc[3] *= r; se *= r;
        m = bm;
        #pragma unroll
        for (int j = 0; j < 8; ++j) {
            const float w = __expf(sc[j] - m);
            acc[0] = fmaf(w, v[j].x, acc[0]);
            acc[1] = fmaf(w, v[j].y, acc[1]);
            acc[2] = fmaf(w, v[j].z, acc[2]);
            acc[3] = fmaf(w, v[j].w, acc[3]);
            se += w;
        }
    }

    ushort4v o;
    o[0] = (ushort)f2bf(acc[0]); o[1] = (ushort)f2bf(acc[1]);
    o[2] = (ushort)f2bf(acc[2]); o[3] = (ushort)f2bf(acc[3]);
    *reinterpret_cast<ushort4v*>(agg + (size_t)n * 64 + sl * 4) = o;
    if (sl == 0) msum[n] = se;
}

// K5: msg = (agg@evW)/(se+eps) + se/(se+eps)*evb ; out = nf + relu(msg@W1+b1)@W2 + b2
// v2: nf prefetched into registers at kernel start (ILP); fragment results
// staged in a wave-private f32 LDS tile (aliasing the bf16 tls region) and
// stored with coalesced float4 writes + residual add.
__global__ __launch_bounds__(256) void k_mega(
    const ushort* __restrict__ agg, const float* __restrict__ msum,
    const ushort* __restrict__ evWt, const float* __restrict__ evb,
    const ushort* __restrict__ W1t, const float* __restrict__ b1,
    const ushort* __restrict__ W2t, const float* __restrict__ b2,
    const float* __restrict__ nf, float* __restrict__ out)
{
    __shared__ float outs[4][16][132];   // 33792 B; low half of each wave's
                                         // slice doubles as the bf16 tls tile
    const int wid  = threadIdx.x >> 6;
    const int lane = threadIdx.x & 63;
    const int n0   = blockIdx.x * 64 + wid * 16;
    if (n0 >= NN) return;                // NN % 16 == 0; wave-private -> safe
    const int r = lane & 15;
    const int g = lane >> 4;

    // ---- nf prefetch: 8 x float4 per lane, coalesced, independent ----
    const int prow  = lane >> 2;         // 16 rows, 4 lanes each
    const int pcol0 = (lane & 3) * 4;
    const float* nfrow = nf + (size_t)(n0 + prow) * 128 + pcol0;
    float4 nfv[8];
    #pragma unroll
    for (int ch = 0; ch < 8; ++ch)
        nfv[ch] = *reinterpret_cast<const float4*>(nfrow + ch * 16);

    ushort* tl = reinterpret_cast<ushort*>(&outs[wid][0][0]);   // [16][136] ushort

    // ---- phase 0: ev GEMM (K=64) + normalize + evb -> msg (bf16, LDS) ----
    short8 aev0 = *reinterpret_cast<const short8*>(agg + (size_t)(n0 + r) * 64 + g * 8);
    short8 aev1 = *reinterpret_cast<const short8*>(agg + (size_t)(n0 + r) * 64 + 32 + g * 8);
    float cf[4], cb[4];
    #pragma unroll
    for (int i = 0; i < 4; ++i) {
        const float s = msum[n0 + g * 4 + i];
        const float c = 1.f / (s + 1e-6f);
        cf[i] = c; cb[i] = s * c;
    }
    #pragma unroll
    for (int nt = 0; nt < 8; ++nt) {
        f32x4 acc = {0.f, 0.f, 0.f, 0.f};
        const short8 b0 = *reinterpret_cast<const short8*>(evWt + (nt * 16 + r) * 64 + g * 8);
        const short8 bq = *reinterpret_cast<const short8*>(evWt + (nt * 16 + r) * 64 + 32 + g * 8);
        acc = __builtin_amdgcn_mfma_f32_16x16x32_bf16(aev0, b0, acc, 0, 0, 0);
        acc = __builtin_amdgcn_mfma_f32_16x16x32_bf16(aev1, bq, acc, 0, 0, 0);
        const float eb = evb[nt * 16 + r];
        #pragma unroll
        for (int i = 0; i < 4; ++i)
            tl[(g * 4 + i) * 136 + nt * 16 + r] = (ushort)f2bf(acc[i] * cf[i] + cb[i] * eb);
    }
    asm volatile("s_waitcnt lgkmcnt(0)" ::: "memory");

    // ---- phase 1: GEMM1 + relu -> h1 (bf16, LDS) ----
    short8 a1[4];
    #pragma unroll
    for (int t = 0; t < 4; ++t)
        a1[t] = *reinterpret_cast<const short8*>(&tl[r * 136 + t * 32 + g * 8]);
    asm volatile("s_waitcnt lgkmcnt(0)" ::: "memory");   // reads done before overwrite
    #pragma unroll
    for (int nt = 0; nt < 8; ++nt) {
        f32x4 acc = {0.f, 0.f, 0.f, 0.f};
        #pragma unroll
        for (int t = 0; t < 4; ++t) {
            const short8 b = *reinterpret_cast<const short8*>(
                W1t + (size_t)(nt * 16 + r) * 128 + t * 32 + g * 8);
            acc = __builtin_amdgcn_mfma_f32_16x16x32_bf16(a1[t], b, acc, 0, 0, 0);
        }
        const float bias = b1[nt * 16 + r];
        #pragma unroll
        for (int i = 0; i < 4; ++i)
            tl[(g * 4 + i) * 136 + nt * 16 + r] = (ushort)f2bf(fmaxf(acc[i] + bias, 0.f));
    }
    asm volatile("s_waitcnt lgkmcnt(0)" ::: "memory");

    // ---- phase 2: GEMM2 + bias -> f32 LDS tile (overwrites tls region) ----
    short8 a2[4];
    #pragma unroll
    for (int t = 0; t < 4; ++t)
        a2[t] = *reinterpret_cast<const short8*>(&tl[r * 136 + t * 32 + g * 8]);
    asm volatile("s_waitcnt lgkmcnt(0)" ::: "memory");   // a2 landed before outs write
    #pragma unroll
    for (int nt = 0; nt < 8; ++nt) {
        f32x4 acc = {0.f, 0.f, 0.f, 0.f};
        #pragma unroll
        for (int t = 0; t < 4; ++t) {
            const short8 b = *reinterpret_cast<const short8*>(
                W2t + (size_t)(nt * 16 + r) * 128 + t * 32 + g * 8);
            acc = __builtin_amdgcn_mfma_f32_16x16x32_bf16(a2[t], b, acc, 0, 0, 0);
        }
        const float bias = b2[nt * 16 + r];
        #pragma unroll
        for (int i = 0; i < 4; ++i)
            outs[wid][g * 4 + i][nt * 16 + r] = acc[i] + bias;
    }
    asm volatile("s_waitcnt lgkmcnt(0)" ::: "memory");

    // ---- epilogue: coalesced float4 residual stores ----
    float* orow = out + (size_t)(n0 + prow) * 128 + pcol0;
    #pragma unroll
    for (int ch = 0; ch < 8; ++ch) {
        const float4 v = *reinterpret_cast<const float4*>(&outs[wid][prow][pcol0 + ch * 16]);
        float4 o;
        o.x = nfv[ch].x + v.x; o.y = nfv[ch].y + v.y;
        o.z = nfv[ch].z + v.z; o.w = nfv[ch].w + v.w;
        *reinterpret_cast<float4*>(orow + ch * 16) = o;
    }
}

extern "C" void kernel_launch(void* const* d_in, const int* in_sizes, int n_in,
                              void* d_out, int out_size, void* d_ws, size_t ws_size,
                              hipStream_t stream)
{
    const float* nf     = (const float*)d_in[0];
    const float* ef     = (const float*)d_in[1];
    const float* attn_W = (const float*)d_in[2];
    const float* evW    = (const float*)d_in[4];
    const float* evb    = (const float*)d_in[5];
    const float* W1     = (const float*)d_in[6];
    const float* b1     = (const float*)d_in[7];
    const float* W2     = (const float*)d_in[8];
    const float* b2     = (const float*)d_in[9];
    const int*   eidx   = (const int*)d_in[10];
    const int*   dst    = eidx + NE;
    float* out = (float*)d_out;

    char* ws = (char*)d_ws;
    int*    count  = (int*)   (ws + 0);          //   400,000
    int*    cursor = (int*)   (ws + 400000);     //   400,000
    int*    rowptr = (int*)   (ws + 800000);     //   400,004 (pad -> 1,200,128)
    float*  msum   = (float*) (ws + 1200128);    //   400,000
    int*    perm   = (int*)   (ws + 1600128);    // 2,560,000
    ushort* agg    = (ushort*)(ws + 4160128);    // 12,800,000
    ushort* W1t    = (ushort*)(ws + 16960128);   //    32,768
    ushort* W2t    = (ushort*)(ws + 16992896);   //    32,768
    ushort* evWt   = (ushort*)(ws + 17025664);   //    16,384
    int*    bsum   = (int*)   (ws + 17042048);   //     1,664  (total ~17.0 MB)

    hipMemsetAsync(count, 0, 800000, stream);    // count + cursor

    k_pre        <<<2500, 256, 0, stream>>>(W1, W2, evW, dst, count, W1t, W2t, evWt);
    k_scan_bsum  <<<NB_SCAN, 256, 0, stream>>>(count, bsum);
    k_scan_final <<<NB_SCAN, 256, 0, stream>>>(count, bsum, rowptr);
    k_permute    <<<2500, 256, 0, stream>>>(dst, rowptr, cursor, perm);
    k_agg_gather <<<6250, 256, 0, stream>>>(ef, attn_W, perm, rowptr, agg, msum);
    k_mega       <<<1563, 256, 0, stream>>>(agg, msum, evWt, evb, W1t, b1, W2t, b2, nf, out);
}

// Round 9
// 185.015 us; speedup vs baseline: 1.0614x; 1.0614x over previous
//
#include <hip/hip_runtime.h>
#include <cstddef>

#define NN 100000
#define NE 640000
#define NB_SCAN 391   // ceil(NN/256)

typedef short  short8   __attribute__((ext_vector_type(8)));
typedef float  f32x4    __attribute__((ext_vector_type(4)));
typedef ushort ushort4v __attribute__((ext_vector_type(4)));

__device__ __forceinline__ short f2bf(float f) {   // RNE f32->bf16
    union { float f; unsigned u; } v; v.f = f;
    unsigned r = (v.u + 0x7fffu + ((v.u >> 16) & 1u)) >> 16;
    return (short)r;
}

// K0: weight bf16-transpose + in-degree histogram. (node_score/attn_b are
// DEAD: per-segment softmax is shift-invariant, the per-dst constant cancels.)
__global__ __launch_bounds__(256) void k_pre(
    const float* __restrict__ W1, const float* __restrict__ W2,
    const float* __restrict__ evW, const int* __restrict__ dst_idx,
    int* __restrict__ count,
    ushort* __restrict__ W1t, ushort* __restrict__ W2t, ushort* __restrict__ evWt)
{
    const int gid = blockIdx.x * 256 + threadIdx.x;   // grid 2500 -> gid < NE
    if (gid < 16384) {
        const int n = gid >> 7, k = gid & 127;
        W1t[gid] = (ushort)f2bf(W1[k * 128 + n]);
        W2t[gid] = (ushort)f2bf(W2[k * 128 + n]);
        if (gid < 8192) {
            const int n2 = gid >> 6, k2 = gid & 63;
            evWt[gid] = (ushort)f2bf(evW[k2 * 128 + n2]);
        }
    }
    atomicAdd(&count[dst_idx[gid]], 1);               // 2500*256 == NE exactly
}

// Scan A: per-block sums
__global__ __launch_bounds__(256) void k_scan_bsum(
    const int* __restrict__ count, int* __restrict__ bsum)
{
    __shared__ int s[256];
    const int t = threadIdx.x, i = blockIdx.x * 256 + t;
    s[t] = (i < NN) ? count[i] : 0;
    __syncthreads();
    for (int off = 128; off; off >>= 1) { if (t < off) s[t] += s[t + off]; __syncthreads(); }
    if (t == 0) bsum[blockIdx.x] = s[0];
}

// Scan B (merged): each block self-computes its prefix over bsum, then
// in-block exclusive scan -> rowptr. Last block writes rowptr[NN] = NE.
__global__ __launch_bounds__(256) void k_scan_final(
    const int* __restrict__ count, const int* __restrict__ bsum,
    int* __restrict__ rowptr)
{
    __shared__ int s[256];
    __shared__ int red[4];
    const int t = threadIdx.x, i = blockIdx.x * 256 + t;
    const int v = (i < NN) ? count[i] : 0;
    s[t] = v;

    int part = 0;
    for (int b = t; b < blockIdx.x; b += 256) part += bsum[b];
    #pragma unroll
    for (int off = 32; off; off >>= 1) part += __shfl_xor(part, off);
    if ((t & 63) == 0) red[t >> 6] = part;
    __syncthreads();
    const int boff = red[0] + red[1] + red[2] + red[3];

    for (int off = 1; off < 256; off <<= 1) {
        const int x = (t >= off) ? s[t - off] : 0;
        __syncthreads();
        s[t] += x;
        __syncthreads();
    }
    if (i < NN) rowptr[i] = boff + s[t] - v;
    if (blockIdx.x == NB_SCAN - 1 && t == 255) rowptr[NN] = boff + s[255];
}

// K2: build permutation grouping edges by dst (CSR)
__global__ __launch_bounds__(256) void k_permute(
    const int* __restrict__ dst_idx, const int* __restrict__ rowptr,
    int* cursor, int* __restrict__ perm)
{
    const int e = blockIdx.x * 256 + threadIdx.x;     // grid 2500 exact
    const int dd = dst_idx[e];
    perm[rowptr[dd] + atomicAdd(&cursor[dd], 1)] = e;
}

// K3: single-pass gather + ONLINE segment softmax + aggregation.
__global__ __launch_bounds__(256) void k_agg_gather(
    const float* __restrict__ ef, const float* __restrict__ attn_W,
    const int* __restrict__ perm, const int* __restrict__ rowptr,
    ushort* __restrict__ agg, float* __restrict__ msum)
{
    const int t  = threadIdx.x;
    const int sl = t & 15;
    const int n  = blockIdx.x * 16 + (t >> 4);   // grid 6250 -> exact
    const int beg = rowptr[n], end = rowptr[n + 1];

    float4 wl;   // mean_h attn_W rows 128+sl*4 .. +3
    {
        const float4 r0 = *reinterpret_cast<const float4*>(attn_W + (128 + sl * 4 + 0) * 4);
        const float4 r1 = *reinterpret_cast<const float4*>(attn_W + (128 + sl * 4 + 1) * 4);
        const float4 r2 = *reinterpret_cast<const float4*>(attn_W + (128 + sl * 4 + 2) * 4);
        const float4 r3 = *reinterpret_cast<const float4*>(attn_W + (128 + sl * 4 + 3) * 4);
        wl.x = 0.25f * (r0.x + r0.y + r0.z + r0.w);
        wl.y = 0.25f * (r1.x + r1.y + r1.z + r1.w);
        wl.z = 0.25f * (r2.x + r2.y + r2.z + r2.w);
        wl.w = 0.25f * (r3.x + r3.y + r3.z + r3.w);
    }

    float m  = -3.0e38f;
    float se = 0.f;
    f32x4 acc = {0.f, 0.f, 0.f, 0.f};

    for (int i = beg; i < end; i += 8) {
        int pe[8];
        #pragma unroll
        for (int j = 0; j < 8; ++j)
            pe[j] = perm[(i + j < end) ? (i + j) : beg];
        float4 v[8];
        #pragma unroll
        for (int j = 0; j < 8; ++j)
            v[j] = *reinterpret_cast<const float4*>(ef + (size_t)pe[j] * 64 + sl * 4);
        float sc[8];
        #pragma unroll
        for (int j = 0; j < 8; ++j) {
            float x = v[j].x * wl.x + v[j].y * wl.y + v[j].z * wl.z + v[j].w * wl.w;
            #pragma unroll
            for (int off = 8; off; off >>= 1) x += __shfl_xor(x, off, 16);
            sc[j] = (i + j < end) ? x : -3.0e38f;
        }
        float bm = m;
        #pragma unroll
        for (int j = 0; j < 8; ++j) bm = fmaxf(bm, sc[j]);
        const float r = __expf(m - bm);
        acc[0] *= r; acc[1] *= r; acc[2] *= r; acc[3] *= r; se *= r;
        m = bm;
        #pragma unroll
        for (int j = 0; j < 8; ++j) {
            const float w = __expf(sc[j] - m);
            acc[0] = fmaf(w, v[j].x, acc[0]);
            acc[1] = fmaf(w, v[j].y, acc[1]);
            acc[2] = fmaf(w, v[j].z, acc[2]);
            acc[3] = fmaf(w, v[j].w, acc[3]);
            se += w;
        }
    }

    ushort4v o;
    o[0] = (ushort)f2bf(acc[0]); o[1] = (ushort)f2bf(acc[1]);
    o[2] = (ushort)f2bf(acc[2]); o[3] = (ushort)f2bf(acc[3]);
    *reinterpret_cast<ushort4v*>(agg + (size_t)n * 64 + sl * 4) = o;
    if (sl == 0) msum[n] = se;
}

// K5 v3: batched B-fragment loads (explicit register arrays -> 16-deep memory
// level parallelism instead of serial load-wait-use chains at VGPR=52).
// __launch_bounds__(256,1) lifts the register cap so the batches get VGPRs.
__global__ __launch_bounds__(256, 1) void k_mega(
    const ushort* __restrict__ agg, const float* __restrict__ msum,
    const ushort* __restrict__ evWt, const float* __restrict__ evb,
    const ushort* __restrict__ W1t, const float* __restrict__ b1,
    const ushort* __restrict__ W2t, const float* __restrict__ b2,
    const float* __restrict__ nf, float* __restrict__ out)
{
    __shared__ float outs[4][16][132];   // 33792 B; doubles as bf16 tl tile
    const int wid  = threadIdx.x >> 6;
    const int lane = threadIdx.x & 63;
    const int n0   = blockIdx.x * 64 + wid * 16;
    if (n0 >= NN) return;                // wave-private, no __syncthreads -> safe
    const int r = lane & 15;
    const int g = lane >> 4;

    // ---- nf prefetch: 8 x float4 per lane, coalesced, independent ----
    const int prow  = lane >> 2;
    const int pcol0 = (lane & 3) * 4;
    const float* nfrow = nf + (size_t)(n0 + prow) * 128 + pcol0;
    float4 nfv[8];
    #pragma unroll
    for (int ch = 0; ch < 8; ++ch)
        nfv[ch] = *reinterpret_cast<const float4*>(nfrow + ch * 16);

    ushort* tl = reinterpret_cast<ushort*>(&outs[wid][0][0]);   // [16][136] ushort

    // ---- phase 0: ev GEMM (K=64): batch 16 B-loads, then MFMA ----
    short8 aev0 = *reinterpret_cast<const short8*>(agg + (size_t)(n0 + r) * 64 + g * 8);
    short8 aev1 = *reinterpret_cast<const short8*>(agg + (size_t)(n0 + r) * 64 + 32 + g * 8);
    short8 bev[16];
    #pragma unroll
    for (int nt = 0; nt < 8; ++nt) {
        bev[nt * 2 + 0] = *reinterpret_cast<const short8*>(evWt + (nt * 16 + r) * 64 + g * 8);
        bev[nt * 2 + 1] = *reinterpret_cast<const short8*>(evWt + (nt * 16 + r) * 64 + 32 + g * 8);
    }
    float cf[4], cb[4];
    #pragma unroll
    for (int i = 0; i < 4; ++i) {
        const float s = msum[n0 + g * 4 + i];
        const float c = 1.f / (s + 1e-6f);
        cf[i] = c; cb[i] = s * c;
    }
    #pragma unroll
    for (int nt = 0; nt < 8; ++nt) {
        f32x4 acc = {0.f, 0.f, 0.f, 0.f};
        acc = __builtin_amdgcn_mfma_f32_16x16x32_bf16(aev0, bev[nt * 2 + 0], acc, 0, 0, 0);
        acc = __builtin_amdgcn_mfma_f32_16x16x32_bf16(aev1, bev[nt * 2 + 1], acc, 0, 0, 0);
        const float eb = evb[nt * 16 + r];
        #pragma unroll
        for (int i = 0; i < 4; ++i)
            tl[(g * 4 + i) * 136 + nt * 16 + r] = (ushort)f2bf(acc[i] * cf[i] + cb[i] * eb);
    }
    asm volatile("s_waitcnt lgkmcnt(0)" ::: "memory");

    // ---- phase 1: GEMM1 + relu -> h1 (bf16, LDS), B in 2 batches of 16 ----
    short8 a1[4];
    #pragma unroll
    for (int t = 0; t < 4; ++t)
        a1[t] = *reinterpret_cast<const short8*>(&tl[r * 136 + t * 32 + g * 8]);
    asm volatile("s_waitcnt lgkmcnt(0)" ::: "memory");   // a1 landed before overwrite
    #pragma unroll
    for (int h = 0; h < 2; ++h) {
        short8 bw[16];
        #pragma unroll
        for (int q = 0; q < 4; ++q)
            #pragma unroll
            for (int t = 0; t < 4; ++t)
                bw[q * 4 + t] = *reinterpret_cast<const short8*>(
                    W1t + (size_t)((h * 4 + q) * 16 + r) * 128 + t * 32 + g * 8);
        #pragma unroll
        for (int q = 0; q < 4; ++q) {
            const int nt = h * 4 + q;
            f32x4 acc = {0.f, 0.f, 0.f, 0.f};
            #pragma unroll
            for (int t = 0; t < 4; ++t)
                acc = __builtin_amdgcn_mfma_f32_16x16x32_bf16(a1[t], bw[q * 4 + t], acc, 0, 0, 0);
            const float bias = b1[nt * 16 + r];
            #pragma unroll
            for (int i = 0; i < 4; ++i)
                tl[(g * 4 + i) * 136 + nt * 16 + r] = (ushort)f2bf(fmaxf(acc[i] + bias, 0.f));
        }
    }
    asm volatile("s_waitcnt lgkmcnt(0)" ::: "memory");

    // ---- phase 2: GEMM2 + bias -> f32 LDS tile, B in 2 batches of 16 ----
    short8 a2[4];
    #pragma unroll
    for (int t = 0; t < 4; ++t)
        a2[t] = *reinterpret_cast<const short8*>(&tl[r * 136 + t * 32 + g * 8]);
    asm volatile("s_waitcnt lgkmcnt(0)" ::: "memory");   // a2 landed before outs write
    #pragma unroll
    for (int h = 0; h < 2; ++h) {
        short8 bw[16];
        #pragma unroll
        for (int q = 0; q < 4; ++q)
            #pragma unroll
            for (int t = 0; t < 4; ++t)
                bw[q * 4 + t] = *reinterpret_cast<const short8*>(
                    W2t + (size_t)((h * 4 + q) * 16 + r) * 128 + t * 32 + g * 8);
        #pragma unroll
        for (int q = 0; q < 4; ++q) {
            const int nt = h * 4 + q;
            f32x4 acc = {0.f, 0.f, 0.f, 0.f};
            #pragma unroll
            for (int t = 0; t < 4; ++t)
                acc = __builtin_amdgcn_mfma_f32_16x16x32_bf16(a2[t], bw[q * 4 + t], acc, 0, 0, 0);
            const float bias = b2[nt * 16 + r];
            #pragma unroll
            for (int i = 0; i < 4; ++i)
                outs[wid][g * 4 + i][nt * 16 + r] = acc[i] + bias;
        }
    }
    asm volatile("s_waitcnt lgkmcnt(0)" ::: "memory");

    // ---- epilogue: coalesced float4 residual stores ----
    float* orow = out + (size_t)(n0 + prow) * 128 + pcol0;
    #pragma unroll
    for (int ch = 0; ch < 8; ++ch) {
        const float4 v = *reinterpret_cast<const float4*>(&outs[wid][prow][pcol0 + ch * 16]);
        float4 o;
        o.x = nfv[ch].x + v.x; o.y = nfv[ch].y + v.y;
        o.z = nfv[ch].z + v.z; o.w = nfv[ch].w + v.w;
        *reinterpret_cast<float4*>(orow + ch * 16) = o;
    }
}

extern "C" void kernel_launch(void* const* d_in, const int* in_sizes, int n_in,
                              void* d_out, int out_size, void* d_ws, size_t ws_size,
                              hipStream_t stream)
{
    const float* nf     = (const float*)d_in[0];
    const float* ef     = (const float*)d_in[1];
    const float* attn_W = (const float*)d_in[2];
    const float* evW    = (const float*)d_in[4];
    const float* evb    = (const float*)d_in[5];
    const float* W1     = (const float*)d_in[6];
    const float* b1     = (const float*)d_in[7];
    const float* W2     = (const float*)d_in[8];
    const float* b2     = (const float*)d_in[9];
    const int*   eidx   = (const int*)d_in[10];
    const int*   dst    = eidx + NE;
    float* out = (float*)d_out;

    char* ws = (char*)d_ws;
    int*    count  = (int*)   (ws + 0);          //   400,000
    int*    cursor = (int*)   (ws + 400000);     //   400,000
    int*    rowptr = (int*)   (ws + 800000);     //   400,004 (pad -> 1,200,128)
    float*  msum   = (float*) (ws + 1200128);    //   400,000
    int*    perm   = (int*)   (ws + 1600128);    // 2,560,000
    ushort* agg    = (ushort*)(ws + 4160128);    // 12,800,000
    ushort* W1t    = (ushort*)(ws + 16960128);   //    32,768
    ushort* W2t    = (ushort*)(ws + 16992896);   //    32,768
    ushort* evWt   = (ushort*)(ws + 17025664);   //    16,384
    int*    bsum   = (int*)   (ws + 17042048);   //     1,664  (total ~17.0 MB)

    hipMemsetAsync(count, 0, 800000, stream);    // count + cursor

    k_pre        <<<2500, 256, 0, stream>>>(W1, W2, evW, dst, count, W1t, W2t, evWt);
    k_scan_bsum  <<<NB_SCAN, 256, 0, stream>>>(count, bsum);
    k_scan_final <<<NB_SCAN, 256, 0, stream>>>(count, bsum, rowptr);
    k_permute    <<<2500, 256, 0, stream>>>(dst, rowptr, cursor, perm);
    k_agg_gather <<<6250, 256, 0, stream>>>(ef, attn_W, perm, rowptr, agg, msum);
    k_mega       <<<1563, 256, 0, stream>>>(agg, msum, evWt, evb, W1t, b1, W2t, b2, nf, out);
}

// Round 10
// 157.768 us; speedup vs baseline: 1.2447x; 1.1727x over previous
//
#include <hip/hip_runtime.h>
#include <cstddef>

#define NN 100000
#define NE 640000
#define NB_SCAN 391   // ceil(NN/256)
#define NTILE 1563    // ceil(NN/64)

typedef short  short8   __attribute__((ext_vector_type(8)));
typedef float  f32x4    __attribute__((ext_vector_type(4)));
typedef ushort ushort4v __attribute__((ext_vector_type(4)));

__device__ __forceinline__ short f2bf(float f) {   // RNE f32->bf16
    union { float f; unsigned u; } v; v.f = f;
    unsigned r = (v.u + 0x7fffu + ((v.u >> 16) & 1u)) >> 16;
    return (short)r;
}

// K0: W2 bf16-transpose + in-degree histogram.
__global__ __launch_bounds__(256) void k_pre(
    const float* __restrict__ W2, const int* __restrict__ dst_idx,
    int* __restrict__ count, ushort* __restrict__ W2t)
{
    const int gid = blockIdx.x * 256 + threadIdx.x;   // grid 2500 -> gid < NE
    if (gid < 16384) {
        const int n = gid >> 7, k = gid & 127;
        W2t[gid] = (ushort)f2bf(W2[k * 128 + n]);
    }
    atomicAdd(&count[dst_idx[gid]], 1);               // 2500*256 == NE exactly
}

// K0b: fused first-layer weights: EVW1[j][n] = sum_c evW[j][c]*W1[c][n]  (bf16, [n][j])
//      EVB1[n] = sum_c evb[c]*W1[c][n]  (f32)
__global__ __launch_bounds__(128) void k_wfuse(
    const float* __restrict__ evW, const float* __restrict__ evb,
    const float* __restrict__ W1,
    ushort* __restrict__ EVW1t, float* __restrict__ EVB1)
{
    const int j = blockIdx.x;     // 0..63
    const int n = threadIdx.x;    // 0..127
    float acc = 0.f;
    #pragma unroll 8
    for (int c = 0; c < 128; ++c)
        acc = fmaf(evW[j * 128 + c], W1[c * 128 + n], acc);
    EVW1t[n * 64 + j] = (ushort)f2bf(acc);
    if (j == 0) {
        float ab = 0.f;
        #pragma unroll 8
        for (int c = 0; c < 128; ++c)
            ab = fmaf(evb[c], W1[c * 128 + n], ab);
        EVB1[n] = ab;
    }
}

// Scan A: per-block sums
__global__ __launch_bounds__(256) void k_scan_bsum(
    const int* __restrict__ count, int* __restrict__ bsum)
{
    __shared__ int s[256];
    const int t = threadIdx.x, i = blockIdx.x * 256 + t;
    s[t] = (i < NN) ? count[i] : 0;
    __syncthreads();
    for (int off = 128; off; off >>= 1) { if (t < off) s[t] += s[t + off]; __syncthreads(); }
    if (t == 0) bsum[blockIdx.x] = s[0];
}

// Scan B (merged): block prefix over bsum + in-block exclusive scan -> rowptr
__global__ __launch_bounds__(256) void k_scan_final(
    const int* __restrict__ count, const int* __restrict__ bsum,
    int* __restrict__ rowptr)
{
    __shared__ int s[256];
    __shared__ int red[4];
    const int t = threadIdx.x, i = blockIdx.x * 256 + t;
    const int v = (i < NN) ? count[i] : 0;
    s[t] = v;

    int part = 0;
    for (int b = t; b < blockIdx.x; b += 256) part += bsum[b];
    #pragma unroll
    for (int off = 32; off; off >>= 1) part += __shfl_xor(part, off);
    if ((t & 63) == 0) red[t >> 6] = part;
    __syncthreads();
    const int boff = red[0] + red[1] + red[2] + red[3];

    for (int off = 1; off < 256; off <<= 1) {
        const int x = (t >= off) ? s[t - off] : 0;
        __syncthreads();
        s[t] += x;
        __syncthreads();
    }
    if (i < NN) rowptr[i] = boff + s[t] - v;
    if (blockIdx.x == NB_SCAN - 1 && t == 255) rowptr[NN] = boff + s[255];
}

// K2: build permutation grouping edges by dst (CSR)
__global__ __launch_bounds__(256) void k_permute(
    const int* __restrict__ dst_idx, const int* __restrict__ rowptr,
    int* cursor, int* __restrict__ perm)
{
    const int e = blockIdx.x * 256 + threadIdx.x;     // grid 2500 exact
    const int dd = dst_idx[e];
    perm[rowptr[dd] + atomicAdd(&cursor[dd], 1)] = e;
}

// K3: single-pass gather + ONLINE segment softmax + aggregation (unchanged).
__global__ __launch_bounds__(256) void k_agg_gather(
    const float* __restrict__ ef, const float* __restrict__ attn_W,
    const int* __restrict__ perm, const int* __restrict__ rowptr,
    ushort* __restrict__ agg, float* __restrict__ msum)
{
    const int t  = threadIdx.x;
    const int sl = t & 15;
    const int n  = blockIdx.x * 16 + (t >> 4);   // grid 6250 -> exact
    const int beg = rowptr[n], end = rowptr[n + 1];

    float4 wl;   // mean_h attn_W rows 128+sl*4 .. +3
    {
        const float4 r0 = *reinterpret_cast<const float4*>(attn_W + (128 + sl * 4 + 0) * 4);
        const float4 r1 = *reinterpret_cast<const float4*>(attn_W + (128 + sl * 4 + 1) * 4);
        const float4 r2 = *reinterpret_cast<const float4*>(attn_W + (128 + sl * 4 + 2) * 4);
        const float4 r3 = *reinterpret_cast<const float4*>(attn_W + (128 + sl * 4 + 3) * 4);
        wl.x = 0.25f * (r0.x + r0.y + r0.z + r0.w);
        wl.y = 0.25f * (r1.x + r1.y + r1.z + r1.w);
        wl.z = 0.25f * (r2.x + r2.y + r2.z + r2.w);
        wl.w = 0.25f * (r3.x + r3.y + r3.z + r3.w);
    }

    float m  = -3.0e38f;
    float se = 0.f;
    f32x4 acc = {0.f, 0.f, 0.f, 0.f};

    for (int i = beg; i < end; i += 8) {
        int pe[8];
        #pragma unroll
        for (int j = 0; j < 8; ++j)
            pe[j] = perm[(i + j < end) ? (i + j) : beg];
        float4 v[8];
        #pragma unroll
        for (int j = 0; j < 8; ++j)
            v[j] = *reinterpret_cast<const float4*>(ef + (size_t)pe[j] * 64 + sl * 4);
        float sc[8];
        #pragma unroll
        for (int j = 0; j < 8; ++j) {
            float x = v[j].x * wl.x + v[j].y * wl.y + v[j].z * wl.z + v[j].w * wl.w;
            #pragma unroll
            for (int off = 8; off; off >>= 1) x += __shfl_xor(x, off, 16);
            sc[j] = (i + j < end) ? x : -3.0e38f;
        }
        float bm = m;
        #pragma unroll
        for (int j = 0; j < 8; ++j) bm = fmaxf(bm, sc[j]);
        const float r = __expf(m - bm);
        acc[0] *= r; acc[1] *= r; acc[2] *= r; acc[3] *= r; se *= r;
        m = bm;
        #pragma unroll
        for (int j = 0; j < 8; ++j) {
            const float w = __expf(sc[j] - m);
            acc[0] = fmaf(w, v[j].x, acc[0]);
            acc[1] = fmaf(w, v[j].y, acc[1]);
            acc[2] = fmaf(w, v[j].z, acc[2]);
            acc[3] = fmaf(w, v[j].w, acc[3]);
            se += w;
        }
    }

    ushort4v o;
    o[0] = (ushort)f2bf(acc[0]); o[1] = (ushort)f2bf(acc[1]);
    o[2] = (ushort)f2bf(acc[2]); o[3] = (ushort)f2bf(acc[3]);
    *reinterpret_cast<ushort4v*>(agg + (size_t)n * 64 + sl * 4) = o;
    if (sl == 0) msum[n] = se;
}

// K5 v4: weights staged ONCE per block in LDS (XOR-swizzled rows), grid-stride
// tile loops. loop1: h1 = relu(cf*(agg@EVW1) + cb*EVB1 + b1) -> h1w (bf16).
// loop2: out = nf + h1@W2 + b2. Same block writes & reads its own h1 tiles;
// __syncthreads (with its vmcnt drain) separates the loops.
__global__ __launch_bounds__(256, 3) void k_mega(
    const ushort* __restrict__ agg, const float* __restrict__ msum,
    const ushort* __restrict__ EVW1t, const float* __restrict__ EVB1,
    const float* __restrict__ b1, const ushort* __restrict__ W2t,
    const float* __restrict__ b2, const float* __restrict__ nf,
    ushort* __restrict__ h1w, float* __restrict__ out)
{
    __shared__ ushort wlds[128 * 128];   // 32 KB: EVW1 rows [n][64] then W2 rows [n][128]
    __shared__ ushort tl[4][16][136];    // 17 KB: per-wave D->row-major staging

    const int tid  = threadIdx.x;
    const int wid  = tid >> 6;
    const int lane = tid & 63;
    const int r    = lane & 15;
    const int g    = lane >> 4;
    const int prow = lane >> 2;          // epilogue/store row mapping
    const int pc   = lane & 3;

    // ---- stage EVW1 (128 rows x 64 ushorts), 16B chunks XOR-swizzled ----
    for (int c = tid; c < 1024; c += 256) {
        const int n = c >> 3, k8 = c & 7;
        *reinterpret_cast<short8*>(&wlds[n * 64 + ((k8 ^ (n & 7)) * 8)]) =
            *reinterpret_cast<const short8*>(EVW1t + n * 64 + k8 * 8);
    }
    __syncthreads();

    float evb1c[8], b1c[8];
    #pragma unroll
    for (int nt = 0; nt < 8; ++nt) {
        evb1c[nt] = EVB1[nt * 16 + r];
        b1c[nt]   = b1[nt * 16 + r];
    }

    // ---- loop1 ----
    for (int bt = blockIdx.x; bt < NTILE; bt += gridDim.x) {
        const int n0 = bt * 64 + wid * 16;
        if (n0 >= NN) continue;          // no syncs inside -> safe
        const short8 aev0 = *reinterpret_cast<const short8*>(agg + (size_t)(n0 + r) * 64 + g * 8);
        const short8 aev1 = *reinterpret_cast<const short8*>(agg + (size_t)(n0 + r) * 64 + 32 + g * 8);
        float cf[4], cb[4];
        #pragma unroll
        for (int i = 0; i < 4; ++i) {
            const float s = msum[n0 + g * 4 + i];
            const float c = 1.f / (s + 1e-6f);
            cf[i] = c; cb[i] = s * c;
        }
        #pragma unroll
        for (int nt = 0; nt < 8; ++nt) {
            const int row = nt * 16 + r;
            const short8 w0 = *reinterpret_cast<const short8*>(
                &wlds[row * 64 + (((0 + g) ^ (r & 7)) * 8)]);
            const short8 w1 = *reinterpret_cast<const short8*>(
                &wlds[row * 64 + (((4 + g) ^ (r & 7)) * 8)]);
            f32x4 acc = {0.f, 0.f, 0.f, 0.f};
            acc = __builtin_amdgcn_mfma_f32_16x16x32_bf16(aev0, w0, acc, 0, 0, 0);
            acc = __builtin_amdgcn_mfma_f32_16x16x32_bf16(aev1, w1, acc, 0, 0, 0);
            #pragma unroll
            for (int i = 0; i < 4; ++i) {
                const float h = fmaxf(cf[i] * acc[i] + cb[i] * evb1c[nt] + b1c[nt], 0.f);
                tl[wid][g * 4 + i][nt * 16 + r] = (ushort)f2bf(h);
            }
        }
        asm volatile("s_waitcnt lgkmcnt(0)" ::: "memory");   // wave-private tl RAW
        ushort* hrow = h1w + (size_t)(n0 + prow) * 128 + pc * 8;
        #pragma unroll
        for (int ch = 0; ch < 4; ++ch)
            *reinterpret_cast<short8*>(hrow + ch * 32) =
                *reinterpret_cast<const short8*>(&tl[wid][prow][pc * 8 + ch * 32]);
    }

    __syncthreads();                     // drains vmcnt: h1w stores complete
    // ---- stage W2 (128 rows x 128 ushorts), swizzled ----
    for (int c = tid; c < 2048; c += 256) {
        const int n = c >> 4, k8 = c & 15;
        *reinterpret_cast<short8*>(&wlds[n * 128 + ((k8 ^ (n & 7)) * 8)]) =
            *reinterpret_cast<const short8*>(W2t + n * 128 + k8 * 8);
    }
    __syncthreads();

    float b2c[8];
    #pragma unroll
    for (int nt = 0; nt < 8; ++nt) b2c[nt] = b2[nt * 16 + r];

    // ---- loop2 (no LDS tile, no fences: compiler schedules freely) ----
    for (int bt = blockIdx.x; bt < NTILE; bt += gridDim.x) {
        const int n0 = bt * 64 + wid * 16;
        if (n0 >= NN) continue;
        short8 a2[4];
        #pragma unroll
        for (int t = 0; t < 4; ++t)
            a2[t] = *reinterpret_cast<const short8*>(
                h1w + (size_t)(n0 + r) * 128 + t * 32 + g * 8);
        #pragma unroll
        for (int nt = 0; nt < 8; ++nt) {
            f32x4 acc = {0.f, 0.f, 0.f, 0.f};
            #pragma unroll
            for (int t = 0; t < 4; ++t) {
                const short8 w = *reinterpret_cast<const short8*>(
                    &wlds[(nt * 16 + r) * 128 + (((t * 4 + g) ^ (r & 7)) * 8)]);
                acc = __builtin_amdgcn_mfma_f32_16x16x32_bf16(a2[t], w, acc, 0, 0, 0);
            }
            #pragma unroll
            for (int i = 0; i < 4; ++i) {
                const size_t idx = (size_t)(n0 + g * 4 + i) * 128 + nt * 16 + r;
                out[idx] = nf[idx] + acc[i] + b2c[nt];
            }
        }
    }
}

extern "C" void kernel_launch(void* const* d_in, const int* in_sizes, int n_in,
                              void* d_out, int out_size, void* d_ws, size_t ws_size,
                              hipStream_t stream)
{
    const float* nf     = (const float*)d_in[0];
    const float* ef     = (const float*)d_in[1];
    const float* attn_W = (const float*)d_in[2];
    const float* evW    = (const float*)d_in[4];
    const float* evb    = (const float*)d_in[5];
    const float* W1     = (const float*)d_in[6];
    const float* b1     = (const float*)d_in[7];
    const float* W2     = (const float*)d_in[8];
    const float* b2     = (const float*)d_in[9];
    const int*   eidx   = (const int*)d_in[10];
    const int*   dst    = eidx + NE;
    float* out = (float*)d_out;

    char* ws = (char*)d_ws;
    int*    count  = (int*)   (ws + 0);          //   400,000
    int*    cursor = (int*)   (ws + 400000);     //   400,000
    int*    rowptr = (int*)   (ws + 800000);     //   400,004 (pad -> 1,200,128)
    float*  msum   = (float*) (ws + 1200128);    //   400,000
    int*    perm   = (int*)   (ws + 1600128);    // 2,560,000
    ushort* agg    = (ushort*)(ws + 4160128);    // 12,800,000
    ushort* W2t    = (ushort*)(ws + 16960128);   //    32,768
    ushort* EVW1t  = (ushort*)(ws + 16992896);   //    16,384
    float*  EVB1   = (float*) (ws + 17009280);   //       512
    int*    bsum   = (int*)   (ws + 17009792);   //     1,664
    ushort* h1w    = (ushort*)(ws + 17011456);   // 25,600,000 (total 42.6 MB < proven 99 MB)

    hipMemsetAsync(count, 0, 800000, stream);    // count + cursor

    k_pre        <<<2500, 256, 0, stream>>>(W2, dst, count, W2t);
    k_wfuse      <<<64,   128, 0, stream>>>(evW, evb, W1, EVW1t, EVB1);
    k_scan_bsum  <<<NB_SCAN, 256, 0, stream>>>(count, bsum);
    k_scan_final <<<NB_SCAN, 256, 0, stream>>>(count, bsum, rowptr);
    k_permute    <<<2500, 256, 0, stream>>>(dst, rowptr, cursor, perm);
    k_agg_gather <<<6250, 256, 0, stream>>>(ef, attn_W, perm, rowptr, agg, msum);
    k_mega       <<<768,  256, 0, stream>>>(agg, msum, EVW1t, EVB1, b1, W2t, b2,
                                            nf, h1w, out);
}

// Round 11
// 145.112 us; speedup vs baseline: 1.3532x; 1.0872x over previous
//
#include <hip/hip_runtime.h>
#include <cstddef>

#define NN 100000
#define NE 640000
#define NB_SCAN 391   // ceil(NN/256)
#define NTILE 1563    // ceil(NN/64)

typedef short  short8   __attribute__((ext_vector_type(8)));
typedef float  f32x4    __attribute__((ext_vector_type(4)));
typedef ushort ushort4v __attribute__((ext_vector_type(4)));

__device__ __forceinline__ short f2bf(float f) {   // RNE f32->bf16
    union { float f; unsigned u; } v; v.f = f;
    unsigned r = (v.u + 0x7fffu + ((v.u >> 16) & 1u)) >> 16;
    return (short)r;
}

// K-1: zero count+cursor (replaces hipMemsetAsync: the captured memset node
// ran as a ~93us tiny-grid fill kernel -- half our runtime since R6).
__global__ __launch_bounds__(256) void k_zero(int4* __restrict__ p) {
    const int i = blockIdx.x * 256 + threadIdx.x;   // grid 196 -> 50176 >= 50000
    if (i < 50000) p[i] = make_int4(0, 0, 0, 0);    // 200000 ints = count+cursor
}

// K0: W2 bf16-transpose + in-degree histogram.
__global__ __launch_bounds__(256) void k_pre(
    const float* __restrict__ W2, const int* __restrict__ dst_idx,
    int* __restrict__ count, ushort* __restrict__ W2t)
{
    const int gid = blockIdx.x * 256 + threadIdx.x;   // grid 2500 -> gid < NE
    if (gid < 16384) {
        const int n = gid >> 7, k = gid & 127;
        W2t[gid] = (ushort)f2bf(W2[k * 128 + n]);
    }
    atomicAdd(&count[dst_idx[gid]], 1);               // 2500*256 == NE exactly
}

// K0b: fused first-layer weights: EVW1[j][n] = sum_c evW[j][c]*W1[c][n] (bf16,[n][j])
//      EVB1[n] = sum_c evb[c]*W1[c][n]  (f32)
__global__ __launch_bounds__(128) void k_wfuse(
    const float* __restrict__ evW, const float* __restrict__ evb,
    const float* __restrict__ W1,
    ushort* __restrict__ EVW1t, float* __restrict__ EVB1)
{
    const int j = blockIdx.x;     // 0..63
    const int n = threadIdx.x;    // 0..127
    float acc = 0.f;
    #pragma unroll 8
    for (int c = 0; c < 128; ++c)
        acc = fmaf(evW[j * 128 + c], W1[c * 128 + n], acc);
    EVW1t[n * 64 + j] = (ushort)f2bf(acc);
    if (j == 0) {
        float ab = 0.f;
        #pragma unroll 8
        for (int c = 0; c < 128; ++c)
            ab = fmaf(evb[c], W1[c * 128 + n], ab);
        EVB1[n] = ab;
    }
}

// Scan A: per-block sums
__global__ __launch_bounds__(256) void k_scan_bsum(
    const int* __restrict__ count, int* __restrict__ bsum)
{
    __shared__ int s[256];
    const int t = threadIdx.x, i = blockIdx.x * 256 + t;
    s[t] = (i < NN) ? count[i] : 0;
    __syncthreads();
    for (int off = 128; off; off >>= 1) { if (t < off) s[t] += s[t + off]; __syncthreads(); }
    if (t == 0) bsum[blockIdx.x] = s[0];
}

// Scan B (merged): block prefix over bsum + in-block exclusive scan -> rowptr
__global__ __launch_bounds__(256) void k_scan_final(
    const int* __restrict__ count, const int* __restrict__ bsum,
    int* __restrict__ rowptr)
{
    __shared__ int s[256];
    __shared__ int red[4];
    const int t = threadIdx.x, i = blockIdx.x * 256 + t;
    const int v = (i < NN) ? count[i] : 0;
    s[t] = v;

    int part = 0;
    for (int b = t; b < blockIdx.x; b += 256) part += bsum[b];
    #pragma unroll
    for (int off = 32; off; off >>= 1) part += __shfl_xor(part, off);
    if ((t & 63) == 0) red[t >> 6] = part;
    __syncthreads();
    const int boff = red[0] + red[1] + red[2] + red[3];

    for (int off = 1; off < 256; off <<= 1) {
        const int x = (t >= off) ? s[t - off] : 0;
        __syncthreads();
        s[t] += x;
        __syncthreads();
    }
    if (i < NN) rowptr[i] = boff + s[t] - v;
    if (blockIdx.x == NB_SCAN - 1 && t == 255) rowptr[NN] = boff + s[255];
}

// K2: build permutation grouping edges by dst (CSR)
__global__ __launch_bounds__(256) void k_permute(
    const int* __restrict__ dst_idx, const int* __restrict__ rowptr,
    int* cursor, int* __restrict__ perm)
{
    const int e = blockIdx.x * 256 + threadIdx.x;     // grid 2500 exact
    const int dd = dst_idx[e];
    perm[rowptr[dd] + atomicAdd(&cursor[dd], 1)] = e;
}

// K3: single-pass gather + ONLINE segment softmax + aggregation (unchanged).
__global__ __launch_bounds__(256) void k_agg_gather(
    const float* __restrict__ ef, const float* __restrict__ attn_W,
    const int* __restrict__ perm, const int* __restrict__ rowptr,
    ushort* __restrict__ agg, float* __restrict__ msum)
{
    const int t  = threadIdx.x;
    const int sl = t & 15;
    const int n  = blockIdx.x * 16 + (t >> 4);   // grid 6250 -> exact
    const int beg = rowptr[n], end = rowptr[n + 1];

    float4 wl;   // mean_h attn_W rows 128+sl*4 .. +3
    {
        const float4 r0 = *reinterpret_cast<const float4*>(attn_W + (128 + sl * 4 + 0) * 4);
        const float4 r1 = *reinterpret_cast<const float4*>(attn_W + (128 + sl * 4 + 1) * 4);
        const float4 r2 = *reinterpret_cast<const float4*>(attn_W + (128 + sl * 4 + 2) * 4);
        const float4 r3 = *reinterpret_cast<const float4*>(attn_W + (128 + sl * 4 + 3) * 4);
        wl.x = 0.25f * (r0.x + r0.y + r0.z + r0.w);
        wl.y = 0.25f * (r1.x + r1.y + r1.z + r1.w);
        wl.z = 0.25f * (r2.x + r2.y + r2.z + r2.w);
        wl.w = 0.25f * (r3.x + r3.y + r3.z + r3.w);
    }

    float m  = -3.0e38f;
    float se = 0.f;
    f32x4 acc = {0.f, 0.f, 0.f, 0.f};

    for (int i = beg; i < end; i += 8) {
        int pe[8];
        #pragma unroll
        for (int j = 0; j < 8; ++j)
            pe[j] = perm[(i + j < end) ? (i + j) : beg];
        float4 v[8];
        #pragma unroll
        for (int j = 0; j < 8; ++j)
            v[j] = *reinterpret_cast<const float4*>(ef + (size_t)pe[j] * 64 + sl * 4);
        float sc[8];
        #pragma unroll
        for (int j = 0; j < 8; ++j) {
            float x = v[j].x * wl.x + v[j].y * wl.y + v[j].z * wl.z + v[j].w * wl.w;
            #pragma unroll
            for (int off = 8; off; off >>= 1) x += __shfl_xor(x, off, 16);
            sc[j] = (i + j < end) ? x : -3.0e38f;
        }
        float bm = m;
        #pragma unroll
        for (int j = 0; j < 8; ++j) bm = fmaxf(bm, sc[j]);
        const float r = __expf(m - bm);
        acc[0] *= r; acc[1] *= r; acc[2] *= r; acc[3] *= r; se *= r;
        m = bm;
        #pragma unroll
        for (int j = 0; j < 8; ++j) {
            const float w = __expf(sc[j] - m);
            acc[0] = fmaf(w, v[j].x, acc[0]);
            acc[1] = fmaf(w, v[j].y, acc[1]);
            acc[2] = fmaf(w, v[j].z, acc[2]);
            acc[3] = fmaf(w, v[j].w, acc[3]);
            se += w;
        }
    }

    ushort4v o;
    o[0] = (ushort)f2bf(acc[0]); o[1] = (ushort)f2bf(acc[1]);
    o[2] = (ushort)f2bf(acc[2]); o[3] = (ushort)f2bf(acc[3]);
    *reinterpret_cast<ushort4v*>(agg + (size_t)n * 64 + sl * 4) = o;
    if (sl == 0) msum[n] = se;
}

// K5 v5: SINGLE PASS. Both weight sets staged once per block in LDS
// (XOR-swizzled); per tile: ev-GEMM -> h1 (wave-private LDS, bf16) -> GEMM2
// -> residual store. No h1 global round-trip. 65 KB LDS -> 2 blocks/CU.
__global__ __launch_bounds__(256, 2) void k_mega(
    const ushort* __restrict__ agg, const float* __restrict__ msum,
    const ushort* __restrict__ EVW1t, const float* __restrict__ EVB1,
    const float* __restrict__ b1, const ushort* __restrict__ W2t,
    const float* __restrict__ b2, const float* __restrict__ nf,
    float* __restrict__ out)
{
    __shared__ ushort wev[128 * 64];     // 16 KB EVW1 rows, swizzled
    __shared__ ushort ww2[128 * 128];    // 32 KB W2 rows, swizzled
    __shared__ ushort tl[4][16][136];    // 17 KB per-wave h1 staging

    const int tid  = threadIdx.x;
    const int wid  = tid >> 6;
    const int lane = tid & 63;
    const int r    = lane & 15;
    const int g    = lane >> 4;

    for (int c = tid; c < 1024; c += 256) {        // EVW1: 1024 x short8
        const int n = c >> 3, k8 = c & 7;
        *reinterpret_cast<short8*>(&wev[n * 64 + ((k8 ^ (n & 7)) * 8)]) =
            *reinterpret_cast<const short8*>(EVW1t + n * 64 + k8 * 8);
    }
    for (int c = tid; c < 2048; c += 256) {        // W2: 2048 x short8
        const int n = c >> 4, k8 = c & 15;
        *reinterpret_cast<short8*>(&ww2[n * 128 + ((k8 ^ (n & 7)) * 8)]) =
            *reinterpret_cast<const short8*>(W2t + n * 128 + k8 * 8);
    }
    __syncthreads();

    float evb1c[8], b1c[8], b2c[8];
    #pragma unroll
    for (int nt = 0; nt < 8; ++nt) {
        evb1c[nt] = EVB1[nt * 16 + r];
        b1c[nt]   = b1[nt * 16 + r];
        b2c[nt]   = b2[nt * 16 + r];
    }

    for (int bt = blockIdx.x; bt < NTILE; bt += gridDim.x) {
        const int n0 = bt * 64 + wid * 16;
        if (n0 >= NN) continue;                    // no syncs in loop -> safe

        const short8 aev0 = *reinterpret_cast<const short8*>(agg + (size_t)(n0 + r) * 64 + g * 8);
        const short8 aev1 = *reinterpret_cast<const short8*>(agg + (size_t)(n0 + r) * 64 + 32 + g * 8);
        float cf[4], cb[4];
        #pragma unroll
        for (int i = 0; i < 4; ++i) {
            const float s = msum[n0 + g * 4 + i];
            const float c = 1.f / (s + 1e-6f);
            cf[i] = c; cb[i] = s * c;
        }

        // ---- fused ev+L1 GEMM (K=64) + relu -> h1 (bf16, wave-private LDS) ----
        #pragma unroll
        for (int nt = 0; nt < 8; ++nt) {
            const int row = nt * 16 + r;
            const short8 w0 = *reinterpret_cast<const short8*>(
                &wev[row * 64 + (((0 + g) ^ (r & 7)) * 8)]);
            const short8 w1 = *reinterpret_cast<const short8*>(
                &wev[row * 64 + (((4 + g) ^ (r & 7)) * 8)]);
            f32x4 acc = {0.f, 0.f, 0.f, 0.f};
            acc = __builtin_amdgcn_mfma_f32_16x16x32_bf16(aev0, w0, acc, 0, 0, 0);
            acc = __builtin_amdgcn_mfma_f32_16x16x32_bf16(aev1, w1, acc, 0, 0, 0);
            #pragma unroll
            for (int i = 0; i < 4; ++i) {
                const float h = fmaxf(cf[i] * acc[i] + cb[i] * evb1c[nt] + b1c[nt], 0.f);
                tl[wid][g * 4 + i][nt * 16 + r] = (ushort)f2bf(h);
            }
        }
        asm volatile("s_waitcnt lgkmcnt(0)" ::: "memory");   // h1 writes landed

        short8 a2[4];
        #pragma unroll
        for (int t = 0; t < 4; ++t)
            a2[t] = *reinterpret_cast<const short8*>(&tl[wid][r][t * 32 + g * 8]);
        asm volatile("s_waitcnt lgkmcnt(0)" ::: "memory");   // reads done before next overwrite

        // ---- GEMM2 + bias + residual ----
        #pragma unroll
        for (int nt = 0; nt < 8; ++nt) {
            f32x4 acc = {0.f, 0.f, 0.f, 0.f};
            #pragma unroll
            for (int t = 0; t < 4; ++t) {
                const short8 w = *reinterpret_cast<const short8*>(
                    &ww2[(nt * 16 + r) * 128 + (((t * 4 + g) ^ (r & 7)) * 8)]);
                acc = __builtin_amdgcn_mfma_f32_16x16x32_bf16(a2[t], w, acc, 0, 0, 0);
            }
            #pragma unroll
            for (int i = 0; i < 4; ++i) {
                const size_t idx = (size_t)(n0 + g * 4 + i) * 128 + nt * 16 + r;
                out[idx] = nf[idx] + acc[i] + b2c[nt];
            }
        }
    }
}

extern "C" void kernel_launch(void* const* d_in, const int* in_sizes, int n_in,
                              void* d_out, int out_size, void* d_ws, size_t ws_size,
                              hipStream_t stream)
{
    const float* nf     = (const float*)d_in[0];
    const float* ef     = (const float*)d_in[1];
    const float* attn_W = (const float*)d_in[2];
    const float* evW    = (const float*)d_in[4];
    const float* evb    = (const float*)d_in[5];
    const float* W1     = (const float*)d_in[6];
    const float* b1     = (const float*)d_in[7];
    const float* W2     = (const float*)d_in[8];
    const float* b2     = (const float*)d_in[9];
    const int*   eidx   = (const int*)d_in[10];
    const int*   dst    = eidx + NE;
    float* out = (float*)d_out;

    char* ws = (char*)d_ws;
    int*    count  = (int*)   (ws + 0);          //   400,000 } contiguous:
    int*    cursor = (int*)   (ws + 400000);     //   400,000 } zeroed by k_zero
    int*    rowptr = (int*)   (ws + 800000);     //   400,004 (pad -> 1,200,128)
    float*  msum   = (float*) (ws + 1200128);    //   400,000
    int*    perm   = (int*)   (ws + 1600128);    // 2,560,000
    ushort* agg    = (ushort*)(ws + 4160128);    // 12,800,000
    ushort* W2t    = (ushort*)(ws + 16960128);   //    32,768
    ushort* EVW1t  = (ushort*)(ws + 16992896);   //    16,384
    float*  EVB1   = (float*) (ws + 17009280);   //       512
    int*    bsum   = (int*)   (ws + 17009792);   //     1,664  (total ~17.0 MB)

    k_zero       <<<196,  256, 0, stream>>>((int4*)count);
    k_pre        <<<2500, 256, 0, stream>>>(W2, dst, count, W2t);
    k_wfuse      <<<64,   128, 0, stream>>>(evW, evb, W1, EVW1t, EVB1);
    k_scan_bsum  <<<NB_SCAN, 256, 0, stream>>>(count, bsum);
    k_scan_final <<<NB_SCAN, 256, 0, stream>>>(count, bsum, rowptr);
    k_permute    <<<2500, 256, 0, stream>>>(dst, rowptr, cursor, perm);
    k_agg_gather <<<6250, 256, 0, stream>>>(ef, attn_W, perm, rowptr, agg, msum);
    k_mega       <<<512,  256, 0, stream>>>(agg, msum, EVW1t, EVB1, b1, W2t, b2, nf, out);
}

// Round 12
// 144.818 us; speedup vs baseline: 1.3560x; 1.0020x over previous
//
#include <hip/hip_runtime.h>
#include <cstddef>

#define NN 100000
#define NE 640000
#define NB_SCAN 391   // ceil(NN/256)
#define NTILE 1563    // ceil(NN/64)

typedef short  short8   __attribute__((ext_vector_type(8)));
typedef float  f32x4    __attribute__((ext_vector_type(4)));
typedef ushort ushort4v __attribute__((ext_vector_type(4)));

__device__ __forceinline__ short f2bf(float f) {   // RNE f32->bf16
    union { float f; unsigned u; } v; v.f = f;
    unsigned r = (v.u + 0x7fffu + ((v.u >> 16) & 1u)) >> 16;
    return (short)r;
}

// K-1 (merged): blocks 0..195 zero count+cursor; blocks 196..259 compute
// fused first-layer weights EVW1 = evW@W1 (bf16 [n][j]) and EVB1 = evb@W1.
__global__ __launch_bounds__(256) void k_init(
    int4* __restrict__ zp, const float* __restrict__ evW,
    const float* __restrict__ evb, const float* __restrict__ W1,
    ushort* __restrict__ EVW1t, float* __restrict__ EVB1)
{
    const int b = blockIdx.x;
    if (b < 196) {
        const int i = b * 256 + threadIdx.x;        // 50176 >= 50000
        if (i < 50000) zp[i] = make_int4(0, 0, 0, 0);
        return;
    }
    if (threadIdx.x >= 128) return;
    const int j = b - 196;        // 0..63
    const int n = threadIdx.x;    // 0..127
    float acc = 0.f;
    #pragma unroll 8
    for (int c = 0; c < 128; ++c)
        acc = fmaf(evW[j * 128 + c], W1[c * 128 + n], acc);
    EVW1t[n * 64 + j] = (ushort)f2bf(acc);
    if (j == 0) {
        float ab = 0.f;
        #pragma unroll 8
        for (int c = 0; c < 128; ++c)
            ab = fmaf(evb[c], W1[c * 128 + n], ab);
        EVB1[n] = ab;
    }
}

// K0: W2 bf16-transpose + in-degree histogram.
__global__ __launch_bounds__(256) void k_pre(
    const float* __restrict__ W2, const int* __restrict__ dst_idx,
    int* __restrict__ count, ushort* __restrict__ W2t)
{
    const int gid = blockIdx.x * 256 + threadIdx.x;   // grid 2500 -> gid < NE
    if (gid < 16384) {
        const int n = gid >> 7, k = gid & 127;
        W2t[gid] = (ushort)f2bf(W2[k * 128 + n]);
    }
    atomicAdd(&count[dst_idx[gid]], 1);               // 2500*256 == NE exactly
}

// Scan A: per-block sums
__global__ __launch_bounds__(256) void k_scan_bsum(
    const int* __restrict__ count, int* __restrict__ bsum)
{
    __shared__ int s[256];
    const int t = threadIdx.x, i = blockIdx.x * 256 + t;
    s[t] = (i < NN) ? count[i] : 0;
    __syncthreads();
    for (int off = 128; off; off >>= 1) { if (t < off) s[t] += s[t + off]; __syncthreads(); }
    if (t == 0) bsum[blockIdx.x] = s[0];
}

// Scan B (merged): block prefix over bsum + in-block exclusive scan -> rowptr
__global__ __launch_bounds__(256) void k_scan_final(
    const int* __restrict__ count, const int* __restrict__ bsum,
    int* __restrict__ rowptr)
{
    __shared__ int s[256];
    __shared__ int red[4];
    const int t = threadIdx.x, i = blockIdx.x * 256 + t;
    const int v = (i < NN) ? count[i] : 0;
    s[t] = v;

    int part = 0;
    for (int b = t; b < blockIdx.x; b += 256) part += bsum[b];
    #pragma unroll
    for (int off = 32; off; off >>= 1) part += __shfl_xor(part, off);
    if ((t & 63) == 0) red[t >> 6] = part;
    __syncthreads();
    const int boff = red[0] + red[1] + red[2] + red[3];

    for (int off = 1; off < 256; off <<= 1) {
        const int x = (t >= off) ? s[t - off] : 0;
        __syncthreads();
        s[t] += x;
        __syncthreads();
    }
    if (i < NN) rowptr[i] = boff + s[t] - v;
    if (blockIdx.x == NB_SCAN - 1 && t == 255) rowptr[NN] = boff + s[255];
}

// K2: build permutation grouping edges by dst (CSR)
__global__ __launch_bounds__(256) void k_permute(
    const int* __restrict__ dst_idx, const int* __restrict__ rowptr,
    int* cursor, int* __restrict__ perm)
{
    const int e = blockIdx.x * 256 + threadIdx.x;     // grid 2500 exact
    const int dd = dst_idx[e];
    perm[rowptr[dd] + atomicAdd(&cursor[dd], 1)] = e;
}

// K3: single-pass gather + ONLINE segment softmax + aggregation.
// v2: 6-deep batches (~50 VGPR) + launch_bounds(256,8) to stay under the
// 64-VGPR occupancy cliff -> 8 waves/SIMD for latency hiding.
__global__ __launch_bounds__(256, 8) void k_agg_gather(
    const float* __restrict__ ef, const float* __restrict__ attn_W,
    const int* __restrict__ perm, const int* __restrict__ rowptr,
    ushort* __restrict__ agg, float* __restrict__ msum)
{
    const int t  = threadIdx.x;
    const int sl = t & 15;
    const int n  = blockIdx.x * 16 + (t >> 4);   // grid 6250 -> exact
    const int beg = rowptr[n], end = rowptr[n + 1];

    float4 wl;   // mean_h attn_W rows 128+sl*4 .. +3
    {
        const float4 r0 = *reinterpret_cast<const float4*>(attn_W + (128 + sl * 4 + 0) * 4);
        const float4 r1 = *reinterpret_cast<const float4*>(attn_W + (128 + sl * 4 + 1) * 4);
        const float4 r2 = *reinterpret_cast<const float4*>(attn_W + (128 + sl * 4 + 2) * 4);
        const float4 r3 = *reinterpret_cast<const float4*>(attn_W + (128 + sl * 4 + 3) * 4);
        wl.x = 0.25f * (r0.x + r0.y + r0.z + r0.w);
        wl.y = 0.25f * (r1.x + r1.y + r1.z + r1.w);
        wl.z = 0.25f * (r2.x + r2.y + r2.z + r2.w);
        wl.w = 0.25f * (r3.x + r3.y + r3.z + r3.w);
    }

    float m  = -3.0e38f;
    float se = 0.f;
    f32x4 acc = {0.f, 0.f, 0.f, 0.f};

    for (int i = beg; i < end; i += 6) {
        int pe[6];
        #pragma unroll
        for (int j = 0; j < 6; ++j)
            pe[j] = perm[(i + j < end) ? (i + j) : beg];
        float4 v[6];
        #pragma unroll
        for (int j = 0; j < 6; ++j)
            v[j] = *reinterpret_cast<const float4*>(ef + (size_t)pe[j] * 64 + sl * 4);
        float sc[6];
        #pragma unroll
        for (int j = 0; j < 6; ++j) {
            float x = v[j].x * wl.x + v[j].y * wl.y + v[j].z * wl.z + v[j].w * wl.w;
            #pragma unroll
            for (int off = 8; off; off >>= 1) x += __shfl_xor(x, off, 16);
            sc[j] = (i + j < end) ? x : -3.0e38f;
        }
        float bm = m;
        #pragma unroll
        for (int j = 0; j < 6; ++j) bm = fmaxf(bm, sc[j]);
        const float r = __expf(m - bm);
        acc[0] *= r; acc[1] *= r; acc[2] *= r; acc[3] *= r; se *= r;
        m = bm;
        #pragma unroll
        for (int j = 0; j < 6; ++j) {
            const float w = __expf(sc[j] - m);
            acc[0] = fmaf(w, v[j].x, acc[0]);
            acc[1] = fmaf(w, v[j].y, acc[1]);
            acc[2] = fmaf(w, v[j].z, acc[2]);
            acc[3] = fmaf(w, v[j].w, acc[3]);
            se += w;
        }
    }

    ushort4v o;
    o[0] = (ushort)f2bf(acc[0]); o[1] = (ushort)f2bf(acc[1]);
    o[2] = (ushort)f2bf(acc[2]); o[3] = (ushort)f2bf(acc[3]);
    *reinterpret_cast<ushort4v*>(agg + (size_t)n * 64 + sl * 4) = o;
    if (sl == 0) msum[n] = se;
}

// K5: SINGLE PASS MLP. Weights staged once per block in LDS (XOR-swizzled);
// per tile: fused ev+L1 GEMM -> h1 (wave-private LDS, bf16) -> GEMM2 -> out.
__global__ __launch_bounds__(256, 2) void k_mega(
    const ushort* __restrict__ agg, const float* __restrict__ msum,
    const ushort* __restrict__ EVW1t, const float* __restrict__ EVB1,
    const float* __restrict__ b1, const ushort* __restrict__ W2t,
    const float* __restrict__ b2, const float* __restrict__ nf,
    float* __restrict__ out)
{
    __shared__ ushort wev[128 * 64];     // 16 KB EVW1 rows, swizzled
    __shared__ ushort ww2[128 * 128];    // 32 KB W2 rows, swizzled
    __shared__ ushort tl[4][16][136];    // 17 KB per-wave h1 staging

    const int tid  = threadIdx.x;
    const int wid  = tid >> 6;
    const int lane = tid & 63;
    const int r    = lane & 15;
    const int g    = lane >> 4;

    for (int c = tid; c < 1024; c += 256) {        // EVW1: 1024 x short8
        const int n = c >> 3, k8 = c & 7;
        *reinterpret_cast<short8*>(&wev[n * 64 + ((k8 ^ (n & 7)) * 8)]) =
            *reinterpret_cast<const short8*>(EVW1t + n * 64 + k8 * 8);
    }
    for (int c = tid; c < 2048; c += 256) {        // W2: 2048 x short8
        const int n = c >> 4, k8 = c & 15;
        *reinterpret_cast<short8*>(&ww2[n * 128 + ((k8 ^ (n & 7)) * 8)]) =
            *reinterpret_cast<const short8*>(W2t + n * 128 + k8 * 8);
    }
    __syncthreads();

    float evb1c[8], b1c[8], b2c[8];
    #pragma unroll
    for (int nt = 0; nt < 8; ++nt) {
        evb1c[nt] = EVB1[nt * 16 + r];
        b1c[nt]   = b1[nt * 16 + r];
        b2c[nt]   = b2[nt * 16 + r];
    }

    for (int bt = blockIdx.x; bt < NTILE; bt += gridDim.x) {
        const int n0 = bt * 64 + wid * 16;
        if (n0 >= NN) continue;                    // no syncs in loop -> safe

        const short8 aev0 = *reinterpret_cast<const short8*>(agg + (size_t)(n0 + r) * 64 + g * 8);
        const short8 aev1 = *reinterpret_cast<const short8*>(agg + (size_t)(n0 + r) * 64 + 32 + g * 8);
        float cf[4], cb[4];
        #pragma unroll
        for (int i = 0; i < 4; ++i) {
            const float s = msum[n0 + g * 4 + i];
            const float c = 1.f / (s + 1e-6f);
            cf[i] = c; cb[i] = s * c;
        }

        #pragma unroll
        for (int nt = 0; nt < 8; ++nt) {
            const int row = nt * 16 + r;
            const short8 w0 = *reinterpret_cast<const short8*>(
                &wev[row * 64 + (((0 + g) ^ (r & 7)) * 8)]);
            const short8 w1 = *reinterpret_cast<const short8*>(
                &wev[row * 64 + (((4 + g) ^ (r & 7)) * 8)]);
            f32x4 acc = {0.f, 0.f, 0.f, 0.f};
            acc = __builtin_amdgcn_mfma_f32_16x16x32_bf16(aev0, w0, acc, 0, 0, 0);
            acc = __builtin_amdgcn_mfma_f32_16x16x32_bf16(aev1, w1, acc, 0, 0, 0);
            #pragma unroll
            for (int i = 0; i < 4; ++i) {
                const float h = fmaxf(cf[i] * acc[i] + cb[i] * evb1c[nt] + b1c[nt], 0.f);
                tl[wid][g * 4 + i][nt * 16 + r] = (ushort)f2bf(h);
            }
        }
        asm volatile("s_waitcnt lgkmcnt(0)" ::: "memory");   // h1 writes landed

        short8 a2[4];
        #pragma unroll
        for (int t = 0; t < 4; ++t)
            a2[t] = *reinterpret_cast<const short8*>(&tl[wid][r][t * 32 + g * 8]);
        asm volatile("s_waitcnt lgkmcnt(0)" ::: "memory");   // reads done before next overwrite

        #pragma unroll
        for (int nt = 0; nt < 8; ++nt) {
            f32x4 acc = {0.f, 0.f, 0.f, 0.f};
            #pragma unroll
            for (int t = 0; t < 4; ++t) {
                const short8 w = *reinterpret_cast<const short8*>(
                    &ww2[(nt * 16 + r) * 128 + (((t * 4 + g) ^ (r & 7)) * 8)]);
                acc = __builtin_amdgcn_mfma_f32_16x16x32_bf16(a2[t], w, acc, 0, 0, 0);
            }
            #pragma unroll
            for (int i = 0; i < 4; ++i) {
                const size_t idx = (size_t)(n0 + g * 4 + i) * 128 + nt * 16 + r;
                out[idx] = nf[idx] + acc[i] + b2c[nt];
            }
        }
    }
}

extern "C" void kernel_launch(void* const* d_in, const int* in_sizes, int n_in,
                              void* d_out, int out_size, void* d_ws, size_t ws_size,
                              hipStream_t stream)
{
    const float* nf     = (const float*)d_in[0];
    const float* ef     = (const float*)d_in[1];
    const float* attn_W = (const float*)d_in[2];
    const float* evW    = (const float*)d_in[4];
    const float* evb    = (const float*)d_in[5];
    const float* W1     = (const float*)d_in[6];
    const float* b1     = (const float*)d_in[7];
    const float* W2     = (const float*)d_in[8];
    const float* b2     = (const float*)d_in[9];
    const int*   eidx   = (const int*)d_in[10];
    const int*   dst    = eidx + NE;
    float* out = (float*)d_out;

    char* ws = (char*)d_ws;
    int*    count  = (int*)   (ws + 0);          //   400,000 } contiguous:
    int*    cursor = (int*)   (ws + 400000);     //   400,000 } zeroed by k_init
    int*    rowptr = (int*)   (ws + 800000);     //   400,004 (pad -> 1,200,128)
    float*  msum   = (float*) (ws + 1200128);    //   400,000
    int*    perm   = (int*)   (ws + 1600128);    // 2,560,000
    ushort* agg    = (ushort*)(ws + 4160128);    // 12,800,000
    ushort* W2t    = (ushort*)(ws + 16960128);   //    32,768
    ushort* EVW1t  = (ushort*)(ws + 16992896);   //    16,384
    float*  EVB1   = (float*) (ws + 17009280);   //       512
    int*    bsum   = (int*)   (ws + 17009792);   //     1,664  (total ~17.0 MB)

    k_init       <<<260,  256, 0, stream>>>((int4*)count, evW, evb, W1, EVW1t, EVB1);
    k_pre        <<<2500, 256, 0, stream>>>(W2, dst, count, W2t);
    k_scan_bsum  <<<NB_SCAN, 256, 0, stream>>>(count, bsum);
    k_scan_final <<<NB_SCAN, 256, 0, stream>>>(count, bsum, rowptr);
    k_permute    <<<2500, 256, 0, stream>>>(dst, rowptr, cursor, perm);
    k_agg_gather <<<6250, 256, 0, stream>>>(ef, attn_W, perm, rowptr, agg, msum);
    k_mega       <<<521,  256, 0, stream>>>(agg, msum, EVW1t, EVB1, b1, W2t, b2, nf, out);
}